// Round 14
// baseline (72.445 us; speedup 1.0000x reference)
//
#include <hip/hip_runtime.h>
#include <math.h>

#define TPB 256
#define DEG 10
#define NMON 286    // C(13,3): monomials x^a y^b z^c with a+b+c <= DEG
#define PCH 16      // point-chunks per monomial: grid = NMON x PCH = 4576 blocks

// Moment factorization: t_ij = u_i . u_j in [-1,1];
//   e^t = sum_k t^k/k!  (deg-10 remainder ~7e-8)
//   Z_i = sum_j e^{t_ij}      = sum_{|a|<=DEG} (M_a / a!) u_i^a
//   S_i = sum_j t_ij e^{t_ij} = sum_{|a|<=DEG} |a| (M_a / a!) u_i^a
// with M_a = sum_j u_j^a. Entropy H_i = ln Z_i - S_i/Z_i - 1e-8*N.
// CTp[chunk][mon] = partial M_mon / (a! b! c!) — pure stores, no init needed.
// rows_kernel sums the PCH partials while building its LDS table and folds
// the |alpha| factor from its own loop variables. All reductions end in pure
// stores (re-poison-safe); result copied to d_out with one async D2D.

// grid (NMON, PCH): each block reduces one 1024-point chunk of one monomial,
// normalizing inline. Branch-free pow via squaring chain + block-uniform
// exponent selects. One pure store per block.
__global__ __launch_bounds__(TPB) void moments_kernel(const float* __restrict__ vel,
                                                      float* __restrict__ CTp, int N) {
    int mon = blockIdx.x;

    // decode mon -> (aa,bb,cc), canonical (a outer, c inner) order
    int rem = mon, aa = 0, bb = 0;
    for (;; ++aa) {
        int R = DEG - aa, cnt = (R + 1) * (R + 2) / 2;
        if (rem < cnt) break;
        rem -= cnt;
    }
    for (;; ++bb) {
        int cnt = DEG - aa - bb + 1;
        if (rem < cnt) break;
        rem -= cnt;
    }
    int cc = rem;

    int base = blockIdx.y * (N / PCH);
    float acc = 0.0f;
#pragma unroll
    for (int q = 0; q < (N / PCH) / TPB; ++q) {
        int j = base + q * TPB + threadIdx.x;
        float x = vel[3 * j], y = vel[3 * j + 1], z = vel[3 * j + 2];
        float n = sqrtf(fmaf(x, x, fmaf(y, y, z * z))) + 1e-6f;
        float r = 1.0f / n;
        x *= r; y *= r; z *= r;
        float x2 = x * x, x4 = x2 * x2, x8 = x4 * x4;
        float y2 = y * y, y4 = y2 * y2, y8 = y4 * y4;
        float z2 = z * z, z4 = z2 * z2, z8 = z4 * z4;
        float m = 1.0f;
        m *= (aa & 1) ? x : 1.0f;  m *= (aa & 2) ? x2 : 1.0f;
        m *= (aa & 4) ? x4 : 1.0f; m *= (aa & 8) ? x8 : 1.0f;
        m *= (bb & 1) ? y : 1.0f;  m *= (bb & 2) ? y2 : 1.0f;
        m *= (bb & 4) ? y4 : 1.0f; m *= (bb & 8) ? y8 : 1.0f;
        m *= (cc & 1) ? z : 1.0f;  m *= (cc & 2) ? z2 : 1.0f;
        m *= (cc & 4) ? z4 : 1.0f; m *= (cc & 8) ? z8 : 1.0f;
        acc += m;
    }

    for (int off = 32; off; off >>= 1) acc += __shfl_down(acc, off);
    __shared__ float red[TPB / 64];
    if ((threadIdx.x & 63) == 0) red[threadIdx.x >> 6] = acc;
    __syncthreads();
    if (threadIdx.x == 0) {
        float Msum = 0.0f;
        for (int w = 0; w < TPB / 64; ++w) Msum += red[w];
        float f = 1.0f;
        for (int q = 2; q <= aa; ++q) f *= (float)q;
        for (int q = 2; q <= bb; ++q) f *= (float)q;
        for (int q = 2; q <= cc; ++q) f *= (float)q;  // <= 10! = 3628800, fp32-exact
        CTp[(size_t)blockIdx.y * NMON + mon] = Msum / f;
    }
}

// Each thread = one row: sum chunk partials into the LDS table, normalize own
// point inline, evaluate Z,S, entropy; per-block partial -> pure store.
__global__ __launch_bounds__(TPB) void rows_kernel(const float* __restrict__ vel,
                                                   const float* __restrict__ CTp,
                                                   float* __restrict__ rowpart, int N) {
    __shared__ float ct[NMON];
    int tid = threadIdx.x;
    for (int k = tid; k < NMON; k += TPB) {
        float s = 0.0f;
#pragma unroll
        for (int ch = 0; ch < PCH; ++ch) s += CTp[(size_t)ch * NMON + k];
        ct[k] = s;
    }
    __syncthreads();

    int i = blockIdx.x * TPB + tid;
    float contrib = 0.0f;
    if (i < N) {
        float x = vel[3 * i], y = vel[3 * i + 1], z = vel[3 * i + 2];
        float n = sqrtf(fmaf(x, x, fmaf(y, y, z * z))) + 1e-6f;
        float r = 1.0f / n;
        x *= r; y *= r; z *= r;

        float Z = 0.f, S = 0.f;
        int idx = 0;
        float xa = 1.f;
        for (int a = 0; a <= DEG; ++a) {
            float yb = 1.f;
            for (int b = 0; b <= DEG - a; ++b) {
                float xy = xa * yb;
                float abf = (float)(a + b);
                float zc = 1.f, cf = 0.f;
                for (int c = 0; c <= DEG - a - b; ++c) {
                    float p = xy * zc * ct[idx];
                    Z += p;
                    S = fmaf(abf + cf, p, S);   // |alpha| * p
                    zc *= z;
                    cf += 1.0f;
                    ++idx;
                }
                yb *= y;
            }
            xa *= x;
        }
        float H = logf(Z) - S / Z - 1e-8f * (float)N;
        contrib = H / (float)N;
    }
    for (int off = 32; off; off >>= 1) contrib += __shfl_down(contrib, off);
    __shared__ float red[TPB / 64];
    if ((tid & 63) == 0) red[tid >> 6] = contrib;
    __syncthreads();
    if (tid == 0) {
        float s = 0.f;
        for (int w = 0; w < TPB / 64; ++w) s += red[w];
        rowpart[blockIdx.x] = s;   // pure store per block (64 blocks)
    }
}

// Sum the per-block partials into result[0]. One wave.
__global__ void finalize_kernel(const float* __restrict__ rowpart,
                                float* __restrict__ result, int nb) {
    float s = 0.0f;
    int lane = threadIdx.x;
    for (int k = lane; k < nb; k += 64) s += rowpart[k];
    for (int off = 32; off; off >>= 1) s += __shfl_down(s, off);
    if (lane == 0) result[0] = s;
}

extern "C" void kernel_launch(void* const* d_in, const int* in_sizes, int n_in,
                              void* d_out, int out_size, void* d_ws, size_t ws_size,
                              hipStream_t stream) {
    const float* vel = (const float*)d_in[0];
    // d_in[1] (positions) is unused by the reference math.
    int N = in_sizes[0] / 3;

    float* CTp = (float*)d_ws;                 // PCH*NMON floats (pure stores)
    float* rowpart = CTp + PCH * NMON;         // 64 floats
    float* result = rowpart + 64;              // 1 float

    int nb = (N + TPB - 1) / TPB;              // 64
    dim3 mg(NMON, PCH);
    moments_kernel<<<mg, TPB, 0, stream>>>(vel, CTp, N);
    rows_kernel<<<nb, TPB, 0, stream>>>(vel, CTp, rowpart, N);
    finalize_kernel<<<1, 64, 0, stream>>>(rowpart, result, nb);
    hipMemcpyAsync(d_out, result, sizeof(float), hipMemcpyDeviceToDevice, stream);
}

// Round 15
// 68.138 us; speedup vs baseline: 1.0632x; 1.0632x over previous
//
#include <hip/hip_runtime.h>
#include <math.h>

#define TPB 256
#define DEG 10
#define NMON 286    // C(13,3): monomials x^a y^b z^c with a+b+c <= DEG
#define PCH 16      // point-chunks per monomial: grid = NMON x PCH = 4576 blocks

// Moment factorization: t_ij = u_i . u_j in [-1,1];
//   e^t = sum_k t^k/k!  (deg-10 remainder ~7e-8)
//   Z_i = sum_j e^{t_ij}      = sum_{|a|<=DEG} (M_a / a!) u_i^a
//   S_i = sum_j t_ij e^{t_ij} = sum_{|a|<=DEG} |a| (M_a / a!) u_i^a
// with M_a = sum_j u_j^a. Entropy H_i = ln Z_i - S_i/Z_i - 1e-8*N.
// Two graph nodes total: moments (pure stores; also zeroes out[0]) then
// rows (atomicAdd of per-block mean partials into out[0]).

// grid (NMON, PCH): each block reduces one 1024-point chunk of one monomial,
// normalizing inline. Branch-free pow via squaring chain + block-uniform
// exponent selects. One pure store per block: CTp[chunk][mon] = partial/a!.
__global__ __launch_bounds__(TPB) void moments_kernel(const float* __restrict__ vel,
                                                      float* __restrict__ CTp,
                                                      float* __restrict__ out, int N) {
    int mon = blockIdx.x;
    if (mon == 0 && blockIdx.y == 0 && threadIdx.x == 0)
        out[0] = 0.0f;   // stream-ordered before rows_kernel's atomics

    // decode mon -> (aa,bb,cc), canonical (a outer, c inner) order
    int rem = mon, aa = 0, bb = 0;
    for (;; ++aa) {
        int R = DEG - aa, cnt = (R + 1) * (R + 2) / 2;
        if (rem < cnt) break;
        rem -= cnt;
    }
    for (;; ++bb) {
        int cnt = DEG - aa - bb + 1;
        if (rem < cnt) break;
        rem -= cnt;
    }
    int cc = rem;

    int base = blockIdx.y * (N / PCH);
    float acc = 0.0f;
#pragma unroll
    for (int q = 0; q < (N / PCH) / TPB; ++q) {
        int j = base + q * TPB + threadIdx.x;
        float x = vel[3 * j], y = vel[3 * j + 1], z = vel[3 * j + 2];
        float n = sqrtf(fmaf(x, x, fmaf(y, y, z * z))) + 1e-6f;
        float r = 1.0f / n;
        x *= r; y *= r; z *= r;
        float x2 = x * x, x4 = x2 * x2, x8 = x4 * x4;
        float y2 = y * y, y4 = y2 * y2, y8 = y4 * y4;
        float z2 = z * z, z4 = z2 * z2, z8 = z4 * z4;
        float m = 1.0f;
        m *= (aa & 1) ? x : 1.0f;  m *= (aa & 2) ? x2 : 1.0f;
        m *= (aa & 4) ? x4 : 1.0f; m *= (aa & 8) ? x8 : 1.0f;
        m *= (bb & 1) ? y : 1.0f;  m *= (bb & 2) ? y2 : 1.0f;
        m *= (bb & 4) ? y4 : 1.0f; m *= (bb & 8) ? y8 : 1.0f;
        m *= (cc & 1) ? z : 1.0f;  m *= (cc & 2) ? z2 : 1.0f;
        m *= (cc & 4) ? z4 : 1.0f; m *= (cc & 8) ? z8 : 1.0f;
        acc += m;
    }

    for (int off = 32; off; off >>= 1) acc += __shfl_down(acc, off);
    __shared__ float red[TPB / 64];
    if ((threadIdx.x & 63) == 0) red[threadIdx.x >> 6] = acc;
    __syncthreads();
    if (threadIdx.x == 0) {
        float Msum = 0.0f;
        for (int w = 0; w < TPB / 64; ++w) Msum += red[w];
        float f = 1.0f;
        for (int q = 2; q <= aa; ++q) f *= (float)q;
        for (int q = 2; q <= bb; ++q) f *= (float)q;
        for (int q = 2; q <= cc; ++q) f *= (float)q;  // <= 10! = 3628800, fp32-exact
        CTp[(size_t)blockIdx.y * NMON + mon] = Msum / f;
    }
}

// Each thread = one row: sum chunk partials into the LDS table (folding the
// |alpha| factor from loop variables), normalize own point inline, evaluate
// Z,S, entropy; block-reduce the mean contribution, one atomicAdd per block.
__global__ __launch_bounds__(TPB) void rows_kernel(const float* __restrict__ vel,
                                                   const float* __restrict__ CTp,
                                                   float* __restrict__ out, int N) {
    __shared__ float ct[NMON];
    int tid = threadIdx.x;
    for (int k = tid; k < NMON; k += TPB) {
        float s = 0.0f;
#pragma unroll
        for (int ch = 0; ch < PCH; ++ch) s += CTp[(size_t)ch * NMON + k];
        ct[k] = s;
    }
    __syncthreads();

    int i = blockIdx.x * TPB + tid;
    float contrib = 0.0f;
    if (i < N) {
        float x = vel[3 * i], y = vel[3 * i + 1], z = vel[3 * i + 2];
        float n = sqrtf(fmaf(x, x, fmaf(y, y, z * z))) + 1e-6f;
        float r = 1.0f / n;
        x *= r; y *= r; z *= r;

        float Z = 0.f, S = 0.f;
        int idx = 0;
        float xa = 1.f;
        for (int a = 0; a <= DEG; ++a) {
            float yb = 1.f;
            for (int b = 0; b <= DEG - a; ++b) {
                float xy = xa * yb;
                float abf = (float)(a + b);
                float zc = 1.f, cf = 0.f;
                for (int c = 0; c <= DEG - a - b; ++c) {
                    float p = xy * zc * ct[idx];
                    Z += p;
                    S = fmaf(abf + cf, p, S);   // |alpha| * p
                    zc *= z;
                    cf += 1.0f;
                    ++idx;
                }
                yb *= y;
            }
            xa *= x;
        }
        float H = logf(Z) - S / Z - 1e-8f * (float)N;
        contrib = H / (float)N;
    }
    for (int off = 32; off; off >>= 1) contrib += __shfl_down(contrib, off);
    __shared__ float red[TPB / 64];
    if ((tid & 63) == 0) red[tid >> 6] = contrib;
    __syncthreads();
    if (tid == 0) {
        float s = 0.f;
        for (int w = 0; w < TPB / 64; ++w) s += red[w];
        atomicAdd(out, s);
    }
}

extern "C" void kernel_launch(void* const* d_in, const int* in_sizes, int n_in,
                              void* d_out, int out_size, void* d_ws, size_t ws_size,
                              hipStream_t stream) {
    const float* vel = (const float*)d_in[0];
    // d_in[1] (positions) is unused by the reference math.
    int N = in_sizes[0] / 3;
    float* out = (float*)d_out;

    float* CTp = (float*)d_ws;   // PCH*NMON floats, pure stores each call

    dim3 mg(NMON, PCH);
    moments_kernel<<<mg, TPB, 0, stream>>>(vel, CTp, out, N);
    rows_kernel<<<(N + TPB - 1) / TPB, TPB, 0, stream>>>(vel, CTp, out, N);
}